// Round 3
// baseline (423.588 us; speedup 1.0000x reference)
//
#include <hip/hip_runtime.h>
#include <cstdint>

#define NPT   4096
#define NBAT  4
#define NS    32
// f64 threshold 0.2*0.2 promotes the f32 d2 compare to: d2 <= (float)0.04
#define R2C   0.04f

// ---- workspace layout (float offsets) ----
#define OFF_XYZ4 0            // B*N float4 (x,y,z,|p|^2)        65536 floats
#define OFF_F1S  65536        // B*N*64: layer1 feature part      1048576
#define OFF_PT   1114112      // B*N*128 pooled (n-major)         2097152
#define OFF_WX   3211264      // 64*4  xyz weights *s1            256
#define OFF_W1T  3211520      // 64x64 W1 feat part, [c][co]*s1   4096
#define OFF_W2T  3215616      // 64x64 W2^T * s2   [c][o]         4096
#define OFF_W3T  3219712      // 64x128 W3^T * s3  [c][o]         8192
#define OFF_IDX  3227904      // B*N*32 int32                     524288 (as int)
// total: 3752192 floats = 14.3 MB

// ---------------- weight prep ----------------
__global__ __launch_bounds__(256) void k_prep(
    const float* __restrict__ W1, const float* __restrict__ s1,
    const float* __restrict__ W2, const float* __restrict__ s2,
    const float* __restrict__ W3, const float* __restrict__ s3,
    float* __restrict__ ws) {
  int i = blockIdx.x * 256 + threadIdx.x;          // 0..8191
  if (i < 256) { int c = i >> 2, d = i & 3;
    ws[OFF_WX + i] = (d < 3) ? W1[c * 67 + d] * s1[c] : 0.f; }
  if (i < 4096) { int c = i >> 6, co = i & 63;
    ws[OFF_W1T + c * 64 + co] = W1[co * 67 + 3 + c] * s1[co]; }
  if (i < 4096) { int c = i >> 6, o = i & 63;
    ws[OFF_W2T + c * 64 + o] = W2[o * 64 + c] * s2[o]; }
  if (i < 8192) { int c = i >> 7, o = i & 127;
    ws[OFF_W3T + c * 128 + o] = W3[o * 64 + c] * s3[o]; }
}

// ---------------- xyz -> float4(x,y,z,sq) ----------------
// sq replicates np: ((x*x + y*y) + z*z), each op individually rounded (no fma)
__global__ __launch_bounds__(256) void k_xyz4(const float* __restrict__ xyz,
                                              float* __restrict__ ws) {
  int i = blockIdx.x * 256 + threadIdx.x;          // 0..16383
  float x = xyz[i * 3], y = xyz[i * 3 + 1], z = xyz[i * 3 + 2];
  float sq = __fadd_rn(__fadd_rn(__fmul_rn(x, x), __fmul_rn(y, y)), __fmul_rn(z, z));
  ((float4*)(ws + OFF_XYZ4))[i] = make_float4(x, y, z, sq);
}

// ---------------- ball query: one wave per center ----------------
__global__ __launch_bounds__(256, 4) void k_bq(const float* __restrict__ ws,
                                               int* __restrict__ idxo) {
  int tid = threadIdx.x, lane = tid & 63;
  int center = blockIdx.x * 4 + (tid >> 6);        // 0..16383
  int b = center >> 12, n = center & 4095;
  const float4* xb = (const float4*)(ws + OFF_XYZ4) + b * NPT;
  float4 cp = xb[n];
  unsigned long long lmask = (1ull << lane) - 1ull;
  int cnt = 0, first = 0;
  for (int ch = 0; ch < NPT / 64; ++ch) {
    int m = ch * 64 + lane;
    float4 p = xb[m];
    // exact np rounding order: dot = ((xx'+yy')+zz'); d2 = (sqn+sqm) - (2*dot)
    float dot = __fadd_rn(__fadd_rn(__fmul_rn(p.x, cp.x), __fmul_rn(p.y, cp.y)),
                          __fmul_rn(p.z, cp.z));
    float d2 = __fsub_rn(__fadd_rn(cp.w, p.w), __fmul_rn(2.f, dot));
    bool hit = d2 <= R2C;                          // f64-promoted '<' == f32 '<='
    unsigned long long mk = __ballot(hit);
    if (mk) {
      if (cnt == 0) first = ch * 64 + __builtin_ctzll(mk);
      int pos = cnt + (int)__popcll(mk & lmask);
      if (hit && pos < NS) idxo[center * NS + pos] = m;
      cnt += (int)__popcll(mk);
      if (cnt >= NS) break;                        // uniform branch
    }
  }
  if (cnt < NS && lane >= cnt && lane < NS) idxo[center * NS + lane] = first;
}

// ---------------- F1s = (W1_feat @ features)*s1 + t1, stored [b][m][co] ----------------
__global__ __launch_bounds__(256, 4) void k_f1(
    const float* __restrict__ feat, const float* __restrict__ t1,
    const float* __restrict__ w1t, float* __restrict__ f1out) {
  int gid = blockIdx.x * 256 + threadIdx.x;        // 0..65535
  int chunk = gid >> 14;                           // 0..3  (16 outputs each)
  int ml = gid & 16383;
  int b = ml >> 12, m = ml & 4095;
  float acc[16];
#pragma unroll
  for (int j = 0; j < 16; ++j) acc[j] = t1[chunk * 16 + j];
#pragma unroll
  for (int c = 0; c < 64; ++c) {
    float f = feat[(b * 64 + c) * NPT + m];        // coalesced
#pragma unroll
    for (int j = 0; j < 16; ++j)
      acc[j] = fmaf(w1t[c * 64 + chunk * 16 + j], f, acc[j]);
  }
  float* o = f1out + (size_t)(b * NPT + m) * 64 + chunk * 16;
#pragma unroll
  for (int j = 0; j < 4; ++j)
    ((float4*)o)[j] = make_float4(acc[4 * j], acc[4 * j + 1], acc[4 * j + 2], acc[4 * j + 3]);
}

// ---------------- main fused MLP + max-pool ----------------
// lane = (center_pair, k): 64 lanes = 2 centers x 32 samples
__global__ __launch_bounds__(256, 2) void k_main(
    const float* __restrict__ ws_c, const int* __restrict__ idx,
    const float* __restrict__ t2, const float* __restrict__ t3,
    float* __restrict__ pooledT) {
  int tid = threadIdx.x, lane = tid & 63;
  int gw = blockIdx.x * 4 + (tid >> 6);            // 0..8191
  int center = gw * 2 + (lane >> 5);               // 0..16383
  int b = center >> 12, n = center & 4095;
  int k = lane & 31;
  int m = idx[center * NS + k];
  const float4* xb = (const float4*)(ws_c + OFF_XYZ4) + b * NPT;
  float4 cp = xb[n], np = xb[m];
  float rx = np.x - cp.x, ry = np.y - cp.y, rz = np.z - cp.z;

  // layer 1: h1 = relu(F1s[m] + Wx*rel)
  const float4* f1 = (const float4*)(ws_c + OFF_F1S + (size_t)(b * NPT + m) * 64);
  float h1[64];
#pragma unroll
  for (int i = 0; i < 16; ++i) {
    float4 q = f1[i];
    h1[4 * i] = q.x; h1[4 * i + 1] = q.y; h1[4 * i + 2] = q.z; h1[4 * i + 3] = q.w;
  }
  const float* wx = ws_c + OFF_WX;
#pragma unroll
  for (int c = 0; c < 64; ++c) {
    float t = fmaf(wx[c * 4 + 2], rz, fmaf(wx[c * 4 + 1], ry, fmaf(wx[c * 4], rx, h1[c])));
    h1[c] = fmaxf(t, 0.f);
  }

  // layer 2: h2 = relu(W2s @ h1 + t2)  (weights via SGPR stream)
  float h2[64];
  const float* W2T = ws_c + OFF_W2T;
#pragma unroll
  for (int ch = 0; ch < 2; ++ch) {
    float acc[32];
#pragma unroll
    for (int j = 0; j < 32; ++j) acc[j] = t2[ch * 32 + j];
#pragma unroll
    for (int c = 0; c < 64; ++c) {
#pragma unroll
      for (int j = 0; j < 32; ++j)
        acc[j] = fmaf(W2T[c * 64 + ch * 32 + j], h1[c], acc[j]);
    }
#pragma unroll
    for (int j = 0; j < 32; ++j) h2[ch * 32 + j] = fmaxf(acc[j], 0.f);
  }

  // layer 3 + relu + max-pool over the 32 k-lanes + store
  const float* W3T = ws_c + OFF_W3T;
  float* op = pooledT + (size_t)center * 128;
#pragma unroll
  for (int ch = 0; ch < 4; ++ch) {
    float acc[32];
#pragma unroll
    for (int j = 0; j < 32; ++j) acc[j] = t3[ch * 32 + j];
#pragma unroll
    for (int c = 0; c < 64; ++c) {
#pragma unroll
      for (int j = 0; j < 32; ++j)
        acc[j] = fmaf(W3T[c * 128 + ch * 32 + j], h2[c], acc[j]);
    }
#pragma unroll
    for (int j = 0; j < 32; ++j) {
      float v = fmaxf(acc[j], 0.f);
      v = fmaxf(v, __shfl_xor(v, 1));
      v = fmaxf(v, __shfl_xor(v, 2));
      v = fmaxf(v, __shfl_xor(v, 4));
      v = fmaxf(v, __shfl_xor(v, 8));
      v = fmaxf(v, __shfl_xor(v, 16));
      acc[j] = v;
    }
    if (k == 0) {                                  // lanes 0 and 32 store both centers
#pragma unroll
      for (int i = 0; i < 8; ++i)
        ((float4*)(op + ch * 32))[i] =
            make_float4(acc[4 * i], acc[4 * i + 1], acc[4 * i + 2], acc[4 * i + 3]);
    }
  }
}

// ---------------- (B,N,128) -> (B,128,N) transpose ----------------
__global__ __launch_bounds__(256) void k_tr(const float* __restrict__ pooledT,
                                            float* __restrict__ out) {
  __shared__ float tile[64][65];
  int b = blockIdx.z;
  int o0 = blockIdx.y * 64;
  int n0 = blockIdx.x * 64;
  int tx = threadIdx.x & 63, ty = threadIdx.x >> 6;
#pragma unroll
  for (int j = 0; j < 16; ++j) {
    int r = j * 4 + ty;
    tile[r][tx] = pooledT[(size_t)(b * NPT + n0 + r) * 128 + o0 + tx];
  }
  __syncthreads();
#pragma unroll
  for (int j = 0; j < 16; ++j) {
    int r = j * 4 + ty;                            // output channel
    out[(size_t)(b * 128 + o0 + r) * NPT + n0 + tx] = tile[tx][r];
  }
}

extern "C" void kernel_launch(void* const* d_in, const int* in_sizes, int n_in,
                              void* d_out, int out_size, void* d_ws, size_t ws_size,
                              hipStream_t stream) {
  const float* xyz = (const float*)d_in[0];
  const float* feat = (const float*)d_in[1];
  const float* W1 = (const float*)d_in[2];
  const float* s1 = (const float*)d_in[3];
  const float* t1 = (const float*)d_in[4];
  const float* W2 = (const float*)d_in[5];
  const float* s2 = (const float*)d_in[6];
  const float* t2 = (const float*)d_in[7];
  const float* W3 = (const float*)d_in[8];
  const float* s3 = (const float*)d_in[9];
  const float* t3 = (const float*)d_in[10];
  float* ws = (float*)d_ws;
  int* idxp = (int*)(ws + OFF_IDX);
  float* out = (float*)d_out;

  // output xyz passthrough
  hipMemcpyAsync(out, xyz, (size_t)NBAT * NPT * 3 * sizeof(float),
                 hipMemcpyDeviceToDevice, stream);

  k_prep<<<32, 256, 0, stream>>>(W1, s1, W2, s2, W3, s3, ws);
  k_xyz4<<<64, 256, 0, stream>>>(xyz, ws);
  k_bq<<<4096, 256, 0, stream>>>(ws, idxp);
  k_f1<<<256, 256, 0, stream>>>(feat, t1, ws + OFF_W1T, ws + OFF_F1S);
  k_main<<<2048, 256, 0, stream>>>(ws, idxp, t2, t3, ws + OFF_PT);
  k_tr<<<dim3(64, 2, 4), 256, 0, stream>>>(ws + OFF_PT, out + NBAT * NPT * 3);
}

// Round 5
// 407.087 us; speedup vs baseline: 1.0405x; 1.0405x over previous
//
#include <hip/hip_runtime.h>
#include <cstdint>

#define NPT   4096
#define NBAT  4
#define NS    32
#define R2C   0.04f
#define NSMP  524288          // B*N*ns total samples

// ---- workspace layout (float offsets) ----
#define OFF_XYZ4 0            // B*N float4 (x,y,z,|p|^2)        65536
#define OFF_F1S  65536        // B*N*64 layer1 feature part      1048576
#define OFF_PT   1114112      // B*N*128 pooled (n-major)        2097152
#define OFF_WX   3211264      // 64*4 xyz weights *s1            256
#define OFF_W1T  3211520      // 64x64 W1 feat [c][co]*s1        4096
#define OFF_W2T  3215616      // 64x64 W2^T*s2 [c][o]            4096
#define OFF_W3T  3219712      // 64x128 W3^T*s3 [c][o]           8192
#define OFF_IDX  3227904      // B*N*32 int32                    524288
#define OFF_H2   3752192      // 16 planes x NSMP x float4       33554432
#define WS_NEED  ((size_t)(OFF_H2 + 33554432) * 4)   // 149226496 B

// ---------------- weight prep ----------------
__global__ __launch_bounds__(256) void k_prep(
    const float* __restrict__ W1, const float* __restrict__ s1,
    const float* __restrict__ W2, const float* __restrict__ s2,
    const float* __restrict__ W3, const float* __restrict__ s3,
    float* __restrict__ ws) {
  int i = blockIdx.x * 256 + threadIdx.x;          // 0..8191
  if (i < 256) { int c = i >> 2, d = i & 3;
    ws[OFF_WX + i] = (d < 3) ? W1[c * 67 + d] * s1[c] : 0.f; }
  if (i < 4096) { int c = i >> 6, co = i & 63;
    ws[OFF_W1T + c * 64 + co] = W1[co * 67 + 3 + c] * s1[co]; }
  if (i < 4096) { int c = i >> 6, o = i & 63;
    ws[OFF_W2T + c * 64 + o] = W2[o * 64 + c] * s2[o]; }
  if (i < 8192) { int c = i >> 7, o = i & 127;
    ws[OFF_W3T + c * 128 + o] = W3[o * 64 + c] * s3[o]; }
}

// ---------------- xyz -> float4(x,y,z,sq); np rounding order, no fma ----------------
__global__ __launch_bounds__(256) void k_xyz4(const float* __restrict__ xyz,
                                              float* __restrict__ ws) {
  int i = blockIdx.x * 256 + threadIdx.x;          // 0..16383
  float x = xyz[i * 3], y = xyz[i * 3 + 1], z = xyz[i * 3 + 2];
  float sq = __fadd_rn(__fadd_rn(__fmul_rn(x, x), __fmul_rn(y, y)), __fmul_rn(z, z));
  ((float4*)(ws + OFF_XYZ4))[i] = make_float4(x, y, z, sq);
}

// ---------------- ball query: wave per center, LDS-staged points ----------------
// 32KB LDS half-tiles (static 64KB limit), prefetched scan, same hit arithmetic
__global__ __launch_bounds__(256, 2) void k_bq(const float* __restrict__ ws,
                                               int* __restrict__ idxo) {
  __shared__ float4 sxb[NPT / 2];                  // 32 KB
  int tid = threadIdx.x, lane = tid & 63;
  int center = blockIdx.x * 4 + (tid >> 6);        // 0..16383
  int b = center >> 12, n = center & 4095;
  const float4* xb = (const float4*)(ws + OFF_XYZ4) + b * NPT;
  float4 cp = xb[n];
  unsigned long long lmask = (1ull << lane) - 1ull;
  int cnt = 0, first = 0;
#pragma unroll 1
  for (int half = 0; half < 2; ++half) {
    __syncthreads();
    for (int i = tid; i < NPT / 2; i += 256) sxb[i] = xb[half * (NPT / 2) + i];
    __syncthreads();
    if (cnt >= NS) continue;                       // wave-uniform skip
    float4 p = sxb[lane];
#pragma unroll 1
    for (int ch = 0; ch < 32; ++ch) {
      float4 pn = sxb[((ch + 1) & 31) * 64 + lane];   // prefetch next chunk
      float dot = __fadd_rn(__fadd_rn(__fmul_rn(p.x, cp.x), __fmul_rn(p.y, cp.y)),
                            __fmul_rn(p.z, cp.z));
      float d2 = __fsub_rn(__fadd_rn(cp.w, p.w), __fmul_rn(2.f, dot));
      bool hit = d2 <= R2C;
      unsigned long long mk = __ballot(hit);
      int m = half * (NPT / 2) + ch * 64 + lane;
      if (mk) {
        if (cnt == 0) first = m - lane + __builtin_ctzll(mk);
        int pos = cnt + (int)__popcll(mk & lmask);
        if (hit && pos < NS) idxo[center * NS + pos] = m;
        cnt += (int)__popcll(mk);
        if (cnt >= NS) break;                      // uniform
      }
      p = pn;
    }
  }
  if (cnt < NS && lane >= cnt && lane < NS) idxo[center * NS + lane] = first;
}

// ---------------- F1s = (W1_feat @ features)*s1 + t1, [b][m][co] ----------------
__global__ __launch_bounds__(256, 4) void k_f1(
    const float* __restrict__ feat, const float* __restrict__ t1,
    const float* __restrict__ w1t, float* __restrict__ f1out) {
  int gid = blockIdx.x * 256 + threadIdx.x;        // 0..65535
  int chunk = gid >> 14, ml = gid & 16383;
  int b = ml >> 12, m = ml & 4095;
  float acc[16];
#pragma unroll
  for (int j = 0; j < 16; ++j) acc[j] = t1[chunk * 16 + j];
#pragma unroll
  for (int c = 0; c < 64; ++c) {
    float f = feat[(b * 64 + c) * NPT + m];
#pragma unroll
    for (int j = 0; j < 16; ++j)
      acc[j] = fmaf(w1t[c * 64 + chunk * 16 + j], f, acc[j]);
  }
  float* o = f1out + (size_t)(b * NPT + m) * 64 + chunk * 16;
#pragma unroll
  for (int j = 0; j < 4; ++j)
    ((float4*)o)[j] = make_float4(acc[4 * j], acc[4 * j + 1], acc[4 * j + 2], acc[4 * j + 3]);
}

// ---------------- layer1+layer2: lane = sample, h2 -> 16 float4-planes ----------------
// live state ~ h1[64]+acc[16] ≈ 92 floats -> no AGPR banking (the round-3 k_main bug)
__global__ __launch_bounds__(256, 3) void k_l2(
    const float* __restrict__ ws_c, const int* __restrict__ idxp,
    const float* __restrict__ t2, float* __restrict__ h2out) {
  int s = blockIdx.x * 256 + threadIdx.x;          // 0..524287
  int center = s >> 5;
  int b = center >> 12, n = center & 4095;
  int m = idxp[s];
  const float4* xb = (const float4*)(ws_c + OFF_XYZ4) + b * NPT;
  float4 cp = xb[n], np = xb[m];
  float rx = np.x - cp.x, ry = np.y - cp.y, rz = np.z - cp.z;

  const float4* f1 = (const float4*)(ws_c + OFF_F1S + (size_t)(b * NPT + m) * 64);
  const float* wx = ws_c + OFF_WX;
  float h1[64];
#pragma unroll
  for (int i = 0; i < 16; ++i) {
    float4 q = f1[i];
    int c = 4 * i;
    h1[c + 0] = fmaxf(fmaf(wx[(c + 0) * 4 + 2], rz, fmaf(wx[(c + 0) * 4 + 1], ry, fmaf(wx[(c + 0) * 4], rx, q.x))), 0.f);
    h1[c + 1] = fmaxf(fmaf(wx[(c + 1) * 4 + 2], rz, fmaf(wx[(c + 1) * 4 + 1], ry, fmaf(wx[(c + 1) * 4], rx, q.y))), 0.f);
    h1[c + 2] = fmaxf(fmaf(wx[(c + 2) * 4 + 2], rz, fmaf(wx[(c + 2) * 4 + 1], ry, fmaf(wx[(c + 2) * 4], rx, q.z))), 0.f);
    h1[c + 3] = fmaxf(fmaf(wx[(c + 3) * 4 + 2], rz, fmaf(wx[(c + 3) * 4 + 1], ry, fmaf(wx[(c + 3) * 4], rx, q.w))), 0.f);
  }

  const float* W2T = ws_c + OFF_W2T;
#pragma unroll
  for (int ch = 0; ch < 4; ++ch) {
    float acc[16];
#pragma unroll
    for (int j = 0; j < 16; ++j) acc[j] = t2[ch * 16 + j];
#pragma unroll
    for (int c = 0; c < 64; ++c) {
#pragma unroll
      for (int j = 0; j < 16; ++j)
        acc[j] = fmaf(W2T[c * 64 + ch * 16 + j], h1[c], acc[j]);
    }
#pragma unroll
    for (int q = 0; q < 4; ++q) {
      float4 v = make_float4(fmaxf(acc[4 * q], 0.f), fmaxf(acc[4 * q + 1], 0.f),
                             fmaxf(acc[4 * q + 2], 0.f), fmaxf(acc[4 * q + 3], 0.f));
      ((float4*)h2out)[(size_t)(4 * ch + q) * NSMP + s] = v;   // coalesced plane store
    }
  }
}

// ---------------- layer3 + relu + pool over 32 samples ----------------
__global__ __launch_bounds__(256, 3) void k_l3(
    const float* __restrict__ h2in, const float* __restrict__ ws_c,
    const float* __restrict__ t3, float* __restrict__ pooledT) {
  int s = blockIdx.x * 256 + threadIdx.x;          // 0..524287
  int center = s >> 5, k = s & 31;
  float h2[64];
#pragma unroll
  for (int p = 0; p < 16; ++p) {
    float4 q = ((const float4*)h2in)[(size_t)p * NSMP + s];    // coalesced plane load
    h2[4 * p] = q.x; h2[4 * p + 1] = q.y; h2[4 * p + 2] = q.z; h2[4 * p + 3] = q.w;
  }
  const float* W3T = ws_c + OFF_W3T;
  float* op = pooledT + (size_t)center * 128;
#pragma unroll
  for (int ch = 0; ch < 8; ++ch) {
    float acc[16];
#pragma unroll
    for (int j = 0; j < 16; ++j) acc[j] = t3[ch * 16 + j];
#pragma unroll
    for (int c = 0; c < 64; ++c) {
#pragma unroll
      for (int j = 0; j < 16; ++j)
        acc[j] = fmaf(W3T[c * 128 + ch * 16 + j], h2[c], acc[j]);
    }
#pragma unroll
    for (int j = 0; j < 16; ++j) {
      float v = fmaxf(acc[j], 0.f);
      v = fmaxf(v, __shfl_xor(v, 1));
      v = fmaxf(v, __shfl_xor(v, 2));
      v = fmaxf(v, __shfl_xor(v, 4));
      v = fmaxf(v, __shfl_xor(v, 8));
      v = fmaxf(v, __shfl_xor(v, 16));
      acc[j] = v;
    }
    if (k == 0) {
#pragma unroll
      for (int q = 0; q < 4; ++q)
        ((float4*)(op + ch * 16))[q] = make_float4(acc[4 * q], acc[4 * q + 1],
                                                   acc[4 * q + 2], acc[4 * q + 3]);
    }
  }
}

// ---------------- fallback fused MLP (round-3 passing version) ----------------
__global__ __launch_bounds__(256, 2) void k_main(
    const float* __restrict__ ws_c, const int* __restrict__ idx,
    const float* __restrict__ t2, const float* __restrict__ t3,
    float* __restrict__ pooledT) {
  int tid = threadIdx.x, lane = tid & 63;
  int gw = blockIdx.x * 4 + (tid >> 6);
  int center = gw * 2 + (lane >> 5);
  int b = center >> 12, n = center & 4095;
  int k = lane & 31;
  int m = idx[center * NS + k];
  const float4* xb = (const float4*)(ws_c + OFF_XYZ4) + b * NPT;
  float4 cp = xb[n], np = xb[m];
  float rx = np.x - cp.x, ry = np.y - cp.y, rz = np.z - cp.z;
  const float4* f1 = (const float4*)(ws_c + OFF_F1S + (size_t)(b * NPT + m) * 64);
  float h1[64];
#pragma unroll
  for (int i = 0; i < 16; ++i) {
    float4 q = f1[i];
    h1[4 * i] = q.x; h1[4 * i + 1] = q.y; h1[4 * i + 2] = q.z; h1[4 * i + 3] = q.w;
  }
  const float* wx = ws_c + OFF_WX;
#pragma unroll
  for (int c = 0; c < 64; ++c) {
    float t = fmaf(wx[c * 4 + 2], rz, fmaf(wx[c * 4 + 1], ry, fmaf(wx[c * 4], rx, h1[c])));
    h1[c] = fmaxf(t, 0.f);
  }
  float h2[64];
  const float* W2T = ws_c + OFF_W2T;
#pragma unroll
  for (int ch = 0; ch < 2; ++ch) {
    float acc[32];
#pragma unroll
    for (int j = 0; j < 32; ++j) acc[j] = t2[ch * 32 + j];
#pragma unroll
    for (int c = 0; c < 64; ++c) {
#pragma unroll
      for (int j = 0; j < 32; ++j)
        acc[j] = fmaf(W2T[c * 64 + ch * 32 + j], h1[c], acc[j]);
    }
#pragma unroll
    for (int j = 0; j < 32; ++j) h2[ch * 32 + j] = fmaxf(acc[j], 0.f);
  }
  const float* W3T = ws_c + OFF_W3T;
  float* op = pooledT + (size_t)center * 128;
#pragma unroll
  for (int ch = 0; ch < 4; ++ch) {
    float acc[32];
#pragma unroll
    for (int j = 0; j < 32; ++j) acc[j] = t3[ch * 32 + j];
#pragma unroll
    for (int c = 0; c < 64; ++c) {
#pragma unroll
      for (int j = 0; j < 32; ++j)
        acc[j] = fmaf(W3T[c * 128 + ch * 32 + j], h2[c], acc[j]);
    }
#pragma unroll
    for (int j = 0; j < 32; ++j) {
      float v = fmaxf(acc[j], 0.f);
      v = fmaxf(v, __shfl_xor(v, 1));
      v = fmaxf(v, __shfl_xor(v, 2));
      v = fmaxf(v, __shfl_xor(v, 4));
      v = fmaxf(v, __shfl_xor(v, 8));
      v = fmaxf(v, __shfl_xor(v, 16));
      acc[j] = v;
    }
    if (k == 0) {
#pragma unroll
      for (int i = 0; i < 8; ++i)
        ((float4*)(op + ch * 32))[i] =
            make_float4(acc[4 * i], acc[4 * i + 1], acc[4 * i + 2], acc[4 * i + 3]);
    }
  }
}

// ---------------- (B,N,128) -> (B,128,N) transpose ----------------
__global__ __launch_bounds__(256) void k_tr(const float* __restrict__ pooledT,
                                            float* __restrict__ out) {
  __shared__ float tile[64][65];
  int b = blockIdx.z;
  int o0 = blockIdx.y * 64, n0 = blockIdx.x * 64;
  int tx = threadIdx.x & 63, ty = threadIdx.x >> 6;
#pragma unroll
  for (int j = 0; j < 16; ++j) {
    int r = j * 4 + ty;
    tile[r][tx] = pooledT[(size_t)(b * NPT + n0 + r) * 128 + o0 + tx];
  }
  __syncthreads();
#pragma unroll
  for (int j = 0; j < 16; ++j) {
    int r = j * 4 + ty;
    out[(size_t)(b * 128 + o0 + r) * NPT + n0 + tx] = tile[tx][r];
  }
}

extern "C" void kernel_launch(void* const* d_in, const int* in_sizes, int n_in,
                              void* d_out, int out_size, void* d_ws, size_t ws_size,
                              hipStream_t stream) {
  const float* xyz = (const float*)d_in[0];
  const float* feat = (const float*)d_in[1];
  const float* W1 = (const float*)d_in[2];
  const float* s1 = (const float*)d_in[3];
  const float* t1 = (const float*)d_in[4];
  const float* W2 = (const float*)d_in[5];
  const float* s2 = (const float*)d_in[6];
  const float* t2 = (const float*)d_in[7];
  const float* W3 = (const float*)d_in[8];
  const float* s3 = (const float*)d_in[9];
  const float* t3 = (const float*)d_in[10];
  float* ws = (float*)d_ws;
  int* idxp = (int*)(ws + OFF_IDX);
  float* out = (float*)d_out;

  hipMemcpyAsync(out, xyz, (size_t)NBAT * NPT * 3 * sizeof(float),
                 hipMemcpyDeviceToDevice, stream);

  k_prep<<<32, 256, 0, stream>>>(W1, s1, W2, s2, W3, s3, ws);
  k_xyz4<<<64, 256, 0, stream>>>(xyz, ws);
  k_bq<<<4096, 256, 0, stream>>>(ws, idxp);
  k_f1<<<256, 256, 0, stream>>>(feat, t1, ws + OFF_W1T, ws + OFF_F1S);
  if (ws_size >= WS_NEED) {                        // host-constant branch: graph-safe
    k_l2<<<2048, 256, 0, stream>>>(ws, idxp, t2, ws + OFF_H2);
    k_l3<<<2048, 256, 0, stream>>>(ws + OFF_H2, ws, t3, ws + OFF_PT);
  } else {
    k_main<<<2048, 256, 0, stream>>>(ws, idxp, t2, t3, ws + OFF_PT);
  }
  k_tr<<<dim3(64, 2, 4), 256, 0, stream>>>(ws + OFF_PT, out + NBAT * NPT * 3);
}